// Round 5
// baseline (3676.444 us; speedup 1.0000x reference)
//
#include <hip/hip_runtime.h>

#define HH 50   // hidden size
#define HP 64   // padded hidden (lanes)
#define RB 8    // batch elements per block
#define TT 512  // timesteps
#define FF 4    // input features

__device__ __forceinline__ float sigm(float x)   { return 1.0f / (1.0f + __expf(-x)); }
__device__ __forceinline__ float tanh_f(float x) { return 1.0f - 2.0f / (1.0f + __expf(2.0f * x)); }

// 8B-aligned float4 gather (weight rows are 200 B apart -> only 8 B aligned)
__device__ __forceinline__ float4 ld4u(const float* p) {
    const float2 a = *(const float2*)p;
    const float2 b = *(const float2*)(p + 2);
    return make_float4(a.x, a.y, b.x, b.y);
}

#define PIN4(V) asm volatile("" : "+v"((V).x), "+v"((V).y), "+v"((V).z), "+v"((V).w));
#define PIN2(V) asm volatile("" : "+v"((V).x), "+v"((V).y));
#define PIN1(S) asm volatile("" : "+v"(S));

// One weight row (50 floats) as named values: 12 float4 + 1 float2.
#define DECLW(P, BASE) \
    float4 P##0  = ld4u((BASE) + 0);  float4 P##1  = ld4u((BASE) + 4);  \
    float4 P##2  = ld4u((BASE) + 8);  float4 P##3  = ld4u((BASE) + 12); \
    float4 P##4  = ld4u((BASE) + 16); float4 P##5  = ld4u((BASE) + 20); \
    float4 P##6  = ld4u((BASE) + 24); float4 P##7  = ld4u((BASE) + 28); \
    float4 P##8  = ld4u((BASE) + 32); float4 P##9  = ld4u((BASE) + 36); \
    float4 P##10 = ld4u((BASE) + 40); float4 P##11 = ld4u((BASE) + 44); \
    float2 P##t  = *(const float2*)((BASE) + 48);

#define PINW(P) \
    PIN4(P##0)  PIN4(P##1)  PIN4(P##2)  PIN4(P##3)  PIN4(P##4)  PIN4(P##5) \
    PIN4(P##6)  PIN4(P##7)  PIN4(P##8)  PIN4(P##9)  PIN4(P##10) PIN4(P##11) \
    PIN2(P##t)

// generic gate j-step: broadcast 8 h-values from LDS (PTR + j*8) + 8 FMA
#define GSTEP(W, PTR, J) { \
    const float4 pa = *(const float4*)((PTR) + (J) * 8); \
    const float4 pb = *(const float4*)((PTR) + (J) * 8 + 4); \
    acc0 = fmaf((W), pa.x, acc0); acc1 = fmaf((W), pa.y, acc1); \
    acc2 = fmaf((W), pa.z, acc2); acc3 = fmaf((W), pa.w, acc3); \
    acc4 = fmaf((W), pb.x, acc4); acc5 = fmaf((W), pb.y, acc5); \
    acc6 = fmaf((W), pb.z, acc6); acc7 = fmaf((W), pb.w, acc7); }
#define GCHUNK(V, PTR, JB) \
    GSTEP((V).x, PTR, (JB)) GSTEP((V).y, PTR, (JB)+1) GSTEP((V).z, PTR, (JB)+2) GSTEP((V).w, PTR, (JB)+3)
#define GALL(P, PTR) \
    GCHUNK(P##0, PTR, 0)  GCHUNK(P##1, PTR, 4)   GCHUNK(P##2, PTR, 8)   GCHUNK(P##3, PTR, 12) \
    GCHUNK(P##4, PTR, 16) GCHUNK(P##5, PTR, 20)  GCHUNK(P##6, PTR, 24)  GCHUNK(P##7, PTR, 28) \
    GCHUNK(P##8, PTR, 32) GCHUNK(P##9, PTR, 36)  GCHUNK(P##10, PTR, 40) GCHUNK(P##11, PTR, 44) \
    GSTEP(P##t.x, PTR, 48) GSTEP(P##t.y, PTR, 49)

#define STORE_G(FN) \
    gbuf[w][0][U] = FN(acc0); gbuf[w][1][U] = FN(acc1); \
    gbuf[w][2][U] = FN(acc2); gbuf[w][3][U] = FN(acc3); \
    gbuf[w][4][U] = FN(acc4); gbuf[w][5][U] = FN(acc5); \
    gbuf[w][6][U] = FN(acc6); gbuf[w][7][U] = FN(acc7);

#define XP(R, A) { const float4 xv = xbuf[tm][R]; \
    A = fmaf(w0v.x, xv.x, fmaf(w0v.y, xv.y, fmaf(w0v.z, xv.z, fmaf(w0v.w, xv.w, bias0)))); }

// ===================== Kernel A: layer-0 recurrence =====================
__launch_bounds__(256)
__global__ void lstm_l0(const float* __restrict__ x,
                        const float* __restrict__ Wih0, const float* __restrict__ Whh0,
                        const float* __restrict__ bih0, const float* __restrict__ bhh0,
                        float* __restrict__ h0seq)
{
    __shared__ __align__(16) float h0buf[HP][RB];
    __shared__ float gbuf[4][RB][HP];
    __shared__ __align__(16) float4 xbuf[64][RB];

    const int tid = threadIdx.x;
    const int w   = tid >> 6;
    const int U   = tid & 63;
    const int g   = blockIdx.x;
    const int b0  = g * RB;
    const int row = w * HH + (U < HH ? U : HH - 1);

    for (int i = tid; i < HP * RB; i += 256) (&h0buf[0][0])[i] = 0.0f;

    DECLW(wA, Whh0 + row * HH)
    float4 w0v   = ld4u(Wih0 + row * FF);
    float  bias0 = bih0[row] + bhh0[row];
    PINW(wA) PIN4(w0v) PIN1(bias0)

    const int r0 = 2 * w, r1 = 2 * w + 1;
    float c0a = 0.0f, c0b = 0.0f;

    __syncthreads();

    for (int t = 0; t < TT; t++) {
        if ((t & 63) == 0) {
            __syncthreads();
            #pragma unroll
            for (int it = 0; it < 2; it++) {
                const int q = tid + it * 256, r = q >> 6, tl = q & 63;
                xbuf[tl][r] = *(const float4*)(x + ((size_t)(b0 + r) * TT + (t + tl)) * FF);
            }
            __syncthreads();
        }
        const int tm = t & 63;

        float acc0, acc1, acc2, acc3, acc4, acc5, acc6, acc7;
        XP(0, acc0) XP(1, acc1) XP(2, acc2) XP(3, acc3)
        XP(4, acc4) XP(5, acc5) XP(6, acc6) XP(7, acc7)
        GALL(wA, &h0buf[0][0])
        if (w == 2) { STORE_G(tanh_f) } else { STORE_G(sigm) }
        __syncthreads();

        {   // elementwise: this wave owns batches r0, r1
            const float i0 = gbuf[0][r0][U], f0 = gbuf[1][r0][U], g0 = gbuf[2][r0][U], o0 = gbuf[3][r0][U];
            c0a = fmaf(f0, c0a, i0 * g0);
            h0buf[U][r0] = o0 * tanh_f(c0a);
            const float i1 = gbuf[0][r1][U], f1 = gbuf[1][r1][U], g1 = gbuf[2][r1][U], o1 = gbuf[3][r1][U];
            c0b = fmaf(f1, c0b, i1 * g1);
            h0buf[U][r1] = o1 * tanh_f(c0b);
        }
        __syncthreads();

        // stream h(t) (first 400 floats of h0buf = [50][8], contiguous) to global
        if (tid < (HH * RB) / 4) {
            const float4 v = *(const float4*)((&h0buf[0][0]) + tid * 4);
            *(float4*)(h0seq + ((size_t)g * TT + t) * (HH * RB) + (size_t)tid * 4) = v;
        }
    }
}

// ===================== Kernel C: layer-1 recurrence + FC =====================
__launch_bounds__(512)
__global__ void lstm_l1(const float* __restrict__ h0seq,
                        const float* __restrict__ Wih1, const float* __restrict__ Whh1,
                        const float* __restrict__ bih1, const float* __restrict__ bhh1,
                        const float* __restrict__ fcW,  const float* __restrict__ fcb,
                        float* __restrict__ out)
{
    __shared__ __align__(16) float xh[16 * HH * RB];   // 16-step chunk of h0, [t][j][r]
    __shared__ __align__(16) float h1buf[HP][RB];
    __shared__ float pI[4][RB][HP];                    // ih partial sums
    __shared__ float pH[4][RB][HP];                    // hh partial sums

    const int tid = threadIdx.x;
    const int w   = tid >> 6;          // 0..3 = ih-gates, 4..7 = hh-gates
    const int U   = tid & 63;
    const int gt  = w & 3;             // gate type i,f,g,o
    const int g   = blockIdx.x;
    const int b0  = g * RB;
    const int Um  = (U < HH ? U : HH - 1);
    const int row = gt * HH + Um;

    for (int i = tid; i < HP * RB; i += 512) (&h1buf[0][0])[i] = 0.0f;

    const float* wbase = (w < 4 ? Wih1 : Whh1) + row * HH;
    DECLW(wW, wbase)
    PINW(wW)

    float bi = 0.0f, bf = 0.0f, bg = 0.0f, bo = 0.0f;
    if (w >= 4) {
        bi = bih1[0 * HH + Um] + bhh1[0 * HH + Um];
        bf = bih1[1 * HH + Um] + bhh1[1 * HH + Um];
        bg = bih1[2 * HH + Um] + bhh1[2 * HH + Um];
        bo = bih1[3 * HH + Um] + bhh1[3 * HH + Um];
    }
    const int r0 = 2 * gt, r1 = r0 + 1;
    float c1a = 0.0f, c1b = 0.0f;

    __syncthreads();

    for (int t = 0; t < TT; t++) {
        if ((t & 15) == 0) {           // stage 16 timesteps of h0 (25.6 KB, coalesced)
            __syncthreads();
            const size_t base = ((size_t)g * TT + t) * (HH * RB);
            for (int i = tid; i < (16 * HH * RB) / 4; i += 512)
                *(float4*)&xh[i * 4] = *(const float4*)(h0seq + base + (size_t)i * 4);
            __syncthreads();
        }
        const int tm = t & 15;

        // phase 1: branchless gate FMA — only the LDS source differs per group
        float acc0 = 0, acc1 = 0, acc2 = 0, acc3 = 0, acc4 = 0, acc5 = 0, acc6 = 0, acc7 = 0;
        const float* P = (w < 4) ? &xh[tm * (HH * RB)] : &h1buf[0][0];
        GALL(wW, P)
        float* pout = (w < 4) ? &pI[gt][0][0] : &pH[gt][0][0];
        pout[0 * HP + U] = acc0; pout[1 * HP + U] = acc1;
        pout[2 * HP + U] = acc2; pout[3 * HP + U] = acc3;
        pout[4 * HP + U] = acc4; pout[5 * HP + U] = acc5;
        pout[6 * HP + U] = acc6; pout[7 * HP + U] = acc7;
        __syncthreads();

        // phase 2 (hh-waves): combine + activations + elementwise for r0, r1
        if (w >= 4) {
            {
                const float gi = pI[0][r0][U] + pH[0][r0][U] + bi;
                const float gf = pI[1][r0][U] + pH[1][r0][U] + bf;
                const float gg = pI[2][r0][U] + pH[2][r0][U] + bg;
                const float go = pI[3][r0][U] + pH[3][r0][U] + bo;
                c1a = fmaf(sigm(gf), c1a, sigm(gi) * tanh_f(gg));
                h1buf[U][r0] = sigm(go) * tanh_f(c1a);
            }
            {
                const float gi = pI[0][r1][U] + pH[0][r1][U] + bi;
                const float gf = pI[1][r1][U] + pH[1][r1][U] + bf;
                const float gg = pI[2][r1][U] + pH[2][r1][U] + bg;
                const float go = pI[3][r1][U] + pH[3][r1][U] + bo;
                c1b = fmaf(sigm(gf), c1b, sigm(gi) * tanh_f(gg));
                h1buf[U][r1] = sigm(go) * tanh_f(c1b);
            }
        }
        __syncthreads();
    }

    // final FC: out[b] = fcW @ h1_T + fcb
    if (tid < 32) {
        const int r  = tid >> 2;
        const int ft = tid & 3;
        float s = fcb[ft];
        #pragma unroll
        for (int j = 0; j < HH; j++) s = fmaf(fcW[ft * HH + j], h1buf[j][r], s);
        out[(size_t)(b0 + r) * FF + ft] = s;
    }
}

// ===================== Fallback: round-4 fused kernel =====================
#define L1_STEP(WI, WH, J) { \
    const float4 pa = *(const float4*)&h0buf[(J)][0]; \
    const float4 pb = *(const float4*)&h0buf[(J)][4]; \
    const float4 qa = *(const float4*)&h1buf[(J)][0]; \
    const float4 qb = *(const float4*)&h1buf[(J)][4]; \
    acc0 = fmaf((WI), pa.x, fmaf((WH), qa.x, acc0)); \
    acc1 = fmaf((WI), pa.y, fmaf((WH), qa.y, acc1)); \
    acc2 = fmaf((WI), pa.z, fmaf((WH), qa.z, acc2)); \
    acc3 = fmaf((WI), pa.w, fmaf((WH), qa.w, acc3)); \
    acc4 = fmaf((WI), pb.x, fmaf((WH), qb.x, acc4)); \
    acc5 = fmaf((WI), pb.y, fmaf((WH), qb.y, acc5)); \
    acc6 = fmaf((WI), pb.z, fmaf((WH), qb.z, acc6)); \
    acc7 = fmaf((WI), pb.w, fmaf((WH), qb.w, acc7)); }
#define L1_CHUNK(VI, VH, JB) \
    L1_STEP((VI).x, (VH).x, (JB))   L1_STEP((VI).y, (VH).y, (JB)+1) \
    L1_STEP((VI).z, (VH).z, (JB)+2) L1_STEP((VI).w, (VH).w, (JB)+3)

__attribute__((amdgpu_waves_per_eu(2, 2)))
__launch_bounds__(256)
__global__ void lstm2_kernel(const float* __restrict__ x,
                             const float* __restrict__ Wih0, const float* __restrict__ Whh0,
                             const float* __restrict__ bih0, const float* __restrict__ bhh0,
                             const float* __restrict__ Wih1, const float* __restrict__ Whh1,
                             const float* __restrict__ bih1, const float* __restrict__ bhh1,
                             const float* __restrict__ fcW,  const float* __restrict__ fcb,
                             float* __restrict__ out)
{
    __shared__ __align__(16) float h0buf[HP][RB];
    __shared__ __align__(16) float h1buf[HP][RB];
    __shared__ float gbuf[4][RB][HP];
    __shared__ __align__(16) float4 xbuf[64][RB];

    const int tid = threadIdx.x;
    const int w   = tid >> 6;
    const int U   = tid & 63;
    const int b0  = blockIdx.x * RB;
    const int row = w * HH + (U < HH ? U : HH - 1);

    for (int i = tid; i < HP * RB; i += 256) {
        (&h0buf[0][0])[i] = 0.0f;
        (&h1buf[0][0])[i] = 0.0f;
    }

    DECLW(wA, Whh0 + row * HH)
    DECLW(wB, Wih1 + row * HH)
    DECLW(wC, Whh1 + row * HH)
    float4 w0v   = ld4u(Wih0 + row * FF);
    float  bias0 = bih0[row] + bhh0[row];
    float  bias1 = bih1[row] + bhh1[row];
    PINW(wA) PINW(wB) PINW(wC)
    PIN4(w0v) PIN1(bias0) PIN1(bias1)

    const int r0 = 2 * w, r1 = 2 * w + 1;
    float c0a = 0.0f, c0b = 0.0f, c1a = 0.0f, c1b = 0.0f;

    __syncthreads();

    for (int t = 0; t < TT; t++) {
        if ((t & 63) == 0) {
            __syncthreads();
            #pragma unroll
            for (int it = 0; it < 2; it++) {
                const int q = tid + it * 256, r = q >> 6, tl = q & 63;
                xbuf[tl][r] = *(const float4*)(x + ((size_t)(b0 + r) * TT + (t + tl)) * FF);
            }
            __syncthreads();
        }
        const int tm = t & 63;

        float acc0, acc1, acc2, acc3, acc4, acc5, acc6, acc7;
        XP(0, acc0) XP(1, acc1) XP(2, acc2) XP(3, acc3)
        XP(4, acc4) XP(5, acc5) XP(6, acc6) XP(7, acc7)
        GALL(wA, &h0buf[0][0])
        if (w == 2) { STORE_G(tanh_f) } else { STORE_G(sigm) }
        __syncthreads();

        {
            const float i0 = gbuf[0][r0][U], f0 = gbuf[1][r0][U], g0 = gbuf[2][r0][U], o0 = gbuf[3][r0][U];
            c0a = fmaf(f0, c0a, i0 * g0);
            h0buf[U][r0] = o0 * tanh_f(c0a);
            const float i1 = gbuf[0][r1][U], f1 = gbuf[1][r1][U], g1 = gbuf[2][r1][U], o1 = gbuf[3][r1][U];
            c0b = fmaf(f1, c0b, i1 * g1);
            h0buf[U][r1] = o1 * tanh_f(c0b);
        }
        __syncthreads();

        acc0 = bias1; acc1 = bias1; acc2 = bias1; acc3 = bias1;
        acc4 = bias1; acc5 = bias1; acc6 = bias1; acc7 = bias1;
        L1_CHUNK(wB0, wC0, 0)   L1_CHUNK(wB1, wC1, 4)   L1_CHUNK(wB2, wC2, 8)
        L1_CHUNK(wB3, wC3, 12)  L1_CHUNK(wB4, wC4, 16)  L1_CHUNK(wB5, wC5, 20)
        L1_CHUNK(wB6, wC6, 24)  L1_CHUNK(wB7, wC7, 28)  L1_CHUNK(wB8, wC8, 32)
        L1_CHUNK(wB9, wC9, 36)  L1_CHUNK(wB10, wC10, 40) L1_CHUNK(wB11, wC11, 44)
        L1_STEP(wBt.x, wCt.x, 48) L1_STEP(wBt.y, wCt.y, 49)
        if (w == 2) { STORE_G(tanh_f) } else { STORE_G(sigm) }
        __syncthreads();

        {
            const float i0 = gbuf[0][r0][U], f0 = gbuf[1][r0][U], g0 = gbuf[2][r0][U], o0 = gbuf[3][r0][U];
            c1a = fmaf(f0, c1a, i0 * g0);
            h1buf[U][r0] = o0 * tanh_f(c1a);
            const float i1 = gbuf[0][r1][U], f1 = gbuf[1][r1][U], g1 = gbuf[2][r1][U], o1 = gbuf[3][r1][U];
            c1b = fmaf(f1, c1b, i1 * g1);
            h1buf[U][r1] = o1 * tanh_f(c1b);
        }
        __syncthreads();
    }

    if (tid < 32) {
        const int r  = tid >> 2;
        const int ft = tid & 3;
        float s = fcb[ft];
        #pragma unroll
        for (int j = 0; j < HH; j++) s = fmaf(fcW[ft * HH + j], h1buf[j][r], s);
        out[(size_t)(b0 + r) * FF + ft] = s;
    }
}

extern "C" void kernel_launch(void* const* d_in, const int* in_sizes, int n_in,
                              void* d_out, int out_size, void* d_ws, size_t ws_size,
                              hipStream_t stream) {
    const float* x    = (const float*)d_in[0];
    const float* Wih0 = (const float*)d_in[1];
    const float* Whh0 = (const float*)d_in[2];
    const float* bih0 = (const float*)d_in[3];
    const float* bhh0 = (const float*)d_in[4];
    const float* Wih1 = (const float*)d_in[5];
    const float* Whh1 = (const float*)d_in[6];
    const float* bih1 = (const float*)d_in[7];
    const float* bhh1 = (const float*)d_in[8];
    const float* fcW  = (const float*)d_in[9];
    const float* fcb  = (const float*)d_in[10];
    float* out = (float*)d_out;

    const int B = in_sizes[0] / (TT * FF);                 // 4096
    const size_t need = (size_t)B * TT * HH * sizeof(float);  // 419.4 MB h0_seq

    if (ws_size >= need) {
        float* h0seq = (float*)d_ws;
        lstm_l0<<<B / RB, 256, 0, stream>>>(x, Wih0, Whh0, bih0, bhh0, h0seq);
        lstm_l1<<<B / RB, 512, 0, stream>>>(h0seq, Wih1, Whh1, bih1, bhh1, fcW, fcb, out);
    } else {
        lstm2_kernel<<<B / RB, 256, 0, stream>>>(x, Wih0, Whh0, bih0, bhh0,
                                                 Wih1, Whh1, bih1, bhh1, fcW, fcb, out);
    }
}